// Round 1
// baseline (495.536 us; speedup 1.0000x reference)
//
#include <hip/hip_runtime.h>
#include <math.h>

#define N_PROP 300
#define N_CLS  80
#define N_GT   24
#define N_B    4
#define CF     128
#define HF     64
#define HM     224
#define TT     28
#define ALPHA  0.25f
#define EPSV   1e-8f
#define CAND_K 10
#define CENTER_R 44.8f
#define S_IMG 896.0f

// ---------- device helpers ----------

__device__ __forceinline__ float iou_unnorm(const float* a, const float* g) {
    float lx = fmaxf(a[0], g[0]), ly = fmaxf(a[1], g[1]);
    float rx = fminf(a[2], g[2]), ry = fminf(a[3], g[3]);
    float w = fmaxf(rx - lx, 0.f), h = fmaxf(ry - ly, 0.f);
    float inter = w * h;
    float aa = fmaxf(a[2] - a[0], 0.f) * fmaxf(a[3] - a[1], 0.f);
    float ag = fmaxf(g[2] - g[0], 0.f) * fmaxf(g[3] - g[1], 0.f);
    float uni = aa + ag - inter;
    return inter / (uni + EPSV);
}

__device__ __forceinline__ float giou_pair(const float* a, const float* g) {
    float lx = fmaxf(a[0], g[0]), ly = fmaxf(a[1], g[1]);
    float rx = fminf(a[2], g[2]), ry = fminf(a[3], g[3]);
    float w = fmaxf(rx - lx, 0.f), h = fmaxf(ry - ly, 0.f);
    float inter = w * h;
    float aa = fmaxf(a[2] - a[0], 0.f) * fmaxf(a[3] - a[1], 0.f);
    float ag = fmaxf(g[2] - g[0], 0.f) * fmaxf(g[3] - g[1], 0.f);
    float uni = aa + ag - inter;
    float iou = inter / (uni + EPSV);
    float elx = fminf(a[0], g[0]), ely = fminf(a[1], g[1]);
    float erx = fmaxf(a[2], g[2]), ery = fmaxf(a[3], g[3]);
    float ew = fmaxf(erx - elx, 0.f), eh = fmaxf(ery - ely, 0.f);
    float enc = ew * eh;
    return iou - (enc - uni) / (enc + EPSV);
}

__device__ __forceinline__ float bilin(const float* img, int H, int W, float X, float Y) {
    float x0f = fminf(fmaxf(floorf(X), 0.f), (float)(W - 1));
    float y0f = fminf(fmaxf(floorf(Y), 0.f), (float)(H - 1));
    float wx = fminf(fmaxf(X - x0f, 0.f), 1.f);
    float wy = fminf(fmaxf(Y - y0f, 0.f), 1.f);
    int x0 = (int)x0f, y0 = (int)y0f;
    int x1 = min(x0 + 1, W - 1), y1 = min(y0 + 1, H - 1);
    float v00 = img[y0 * W + x0], v01 = img[y0 * W + x1];
    float v10 = img[y1 * W + x0], v11 = img[y1 * W + x1];
    return v00 * (1.f - wx) * (1.f - wy) + v01 * wx * (1.f - wy)
         + v10 * (1.f - wx) * wy + v11 * wx * wy;
}

// ---------- kernels ----------

__global__ void zero_acc(float* acc) {
    if (threadIdx.x < 8) acc[threadIdx.x] = 0.f;
}

// one block per image: SimOTA matching
__global__ __launch_bounds__(256) void match_kernel(
    const float* __restrict__ logits, const float* __restrict__ boxes,
    const int* __restrict__ gtcls, const float* __restrict__ gtbox,
    float* __restrict__ w_val, int* __restrict__ gt_ind)
{
    int b = blockIdx.x;
    int tid = threadIdx.x;
    __shared__ float s_box[N_PROP][4];
    __shared__ float s_gtb[N_GT][4];
    __shared__ int   s_gtc[N_GT];
    __shared__ float s_cost[N_PROP][N_GT];   // 28.8 KB
    __shared__ int   s_valid[N_PROP];
    __shared__ int   s_dynk[N_GT];
    __shared__ int   s_match[N_PROP];

    for (int k = tid; k < N_PROP * 4; k += 256) ((float*)s_box)[k] = boxes[b * N_PROP * 4 + k];
    for (int k = tid; k < N_GT * 4; k += 256)   ((float*)s_gtb)[k] = gtbox[b * N_GT * 4 + k];
    if (tid < N_GT) s_gtc[tid] = gtcls[b * N_GT + tid];
    __syncthreads();

    // valid flags
    for (int i = tid; i < N_PROP; i += 256) {
        float cx = (s_box[i][0] + s_box[i][2]) * 0.5f;
        float cy = (s_box[i][1] + s_box[i][3]) * 0.5f;
        int v = 0;
        for (int j = 0; j < N_GT; j++) {
            int in_gt = (cx >= s_gtb[j][0]) & (cx <= s_gtb[j][2]) &
                        (cy >= s_gtb[j][1]) & (cy <= s_gtb[j][3]);
            float gcx = (s_gtb[j][0] + s_gtb[j][2]) * 0.5f;
            float gcy = (s_gtb[j][1] + s_gtb[j][3]) * 0.5f;
            int in_ct = (fabsf(cx - gcx) <= CENTER_R) & (fabsf(cy - gcy) <= CENTER_R);
            v |= (in_gt | in_ct);
        }
        s_valid[i] = v;
        s_match[i] = 0;
    }
    __syncthreads();

    // cost matrix
    for (int e = tid; e < N_PROP * N_GT; e += 256) {
        int i = e / N_GT, j = e % N_GT;
        const float* a = s_box[i];
        const float* g = s_gtb[j];
        float cx = (a[0] + a[2]) * 0.5f;
        float cy = (a[1] + a[3]) * 0.5f;
        int in_gt = (cx >= g[0]) & (cx <= g[2]) & (cy >= g[1]) & (cy <= g[3]);
        float gcx = (g[0] + g[2]) * 0.5f;
        float gcy = (g[1] + g[3]) * 0.5f;
        int in_ct = (fabsf(cx - gcx) <= CENTER_R) & (fabsf(cy - gcy) <= CENTER_R);
        int in_both = in_gt & in_ct;

        // FocalLossCost at gt class
        float x = logits[(b * N_PROP + i) * N_CLS + s_gtc[j]];
        float p = 1.f / (1.f + expf(-x));
        float neg = (-logf(1.f - p + EPSV)) * (1.f - ALPHA) * (p * p);
        float pos = (-logf(p + EPSV)) * ALPHA * ((1.f - p) * (1.f - p));
        float clsc = 2.0f * (pos - neg);

        // normalized boxes
        float nb[4], ng[4];
        for (int k = 0; k < 4; k++) { nb[k] = a[k] / S_IMG; ng[k] = g[k] / S_IMG; }
        float l1 = 5.0f * (((fabsf(nb[0] - ng[0]) + fabsf(nb[1] - ng[1]))
                            + fabsf(nb[2] - ng[2])) + fabsf(nb[3] - ng[3]));
        float ngiou = giou_pair(nb, ng);

        float cst = clsc + l1;
        cst = cst + 2.0f * (1.f - ngiou);
        cst = cst + (in_both ? 0.f : 1e5f);
        cst = cst + (s_valid[i] ? 0.f : 1e9f);
        s_cost[i][j] = cst;
    }
    __syncthreads();

    // dynamic-k: top-10 iou sum per gt
    if (tid < N_GT) {
        float t[CAND_K];
        for (int k = 0; k < CAND_K; k++) t[k] = 0.f;
        for (int i = 0; i < N_PROP; i++) {
            float v = s_valid[i] ? iou_unnorm(s_box[i], s_gtb[tid]) : 0.f;
            if (v > t[CAND_K - 1]) {
                int k = CAND_K - 1;
                while (k > 0 && t[k - 1] < v) { t[k] = t[k - 1]; k--; }
                t[k] = v;
            }
        }
        float s = 0.f;
        for (int k = 0; k < CAND_K; k++) s += t[k];
        int dk = (int)s;
        dk = max(1, min(dk, N_PROP));
        s_dynk[tid] = dk;
    }
    __syncthreads();

    // stable rank per column; matching bits
    for (int e = tid; e < N_PROP * N_GT; e += 256) {
        int i = e / N_GT, j = e % N_GT;
        if (!s_valid[i]) continue;
        float ci = s_cost[i][j];
        int r = 0;
        for (int k = 0; k < N_PROP; k++) {
            float ck = s_cost[k][j];
            r += (ck < ci) || (ck == ci && k < i);
        }
        if (r < s_dynk[j]) atomicOr(&s_match[i], 1 << j);
    }
    __syncthreads();

    // per-row resolution
    for (int i = tid; i < N_PROP; i += 256) {
        float bestc = s_cost[i][0];
        int best = 0;
        for (int j = 1; j < N_GT; j++) {
            float cc = s_cost[i][j];
            if (cc < bestc) { bestc = cc; best = j; }
        }
        int msk = s_match[i];
        if (__popc(msk) > 1) msk = 1 << best;
        int gi = msk ? (__ffs(msk) - 1) : best;
        gt_ind[b * N_PROP + i] = gi;
        w_val[b * N_PROP + i] = s_valid[i] ? 1.0f : 0.0f;
    }
}

// focal classification loss over all (b, n, c)
__global__ __launch_bounds__(256) void cls_kernel(
    const float* __restrict__ logits, const int* __restrict__ gtcls,
    const float* __restrict__ w_val, const int* __restrict__ gt_ind,
    float* __restrict__ acc)
{
    int e = blockIdx.x * 256 + threadIdx.x;
    float term = 0.f;
    if (e < N_B * N_PROP * N_CLS) {
        int cls = e % N_CLS;
        int bi = e / N_CLS;
        int b = bi / N_PROP;
        float x = logits[e];
        int gi = gt_ind[bi];
        int mc = gtcls[b * N_GT + gi];
        float w = w_val[bi];
        float label = (cls == mc) ? w : 0.f;
        float p = 1.f / (1.f + expf(-x));
        float ce = fmaxf(x, 0.f) + log1pf(expf(-fabsf(x))) - x * label;
        float pt = p * label + (1.f - p) * (1.f - label);
        float at = ALPHA * label + (1.f - ALPHA) * (1.f - label);
        term = at * (1.f - pt) * (1.f - pt) * ce;
    }
    __shared__ float red[256];
    red[threadIdx.x] = term;
    __syncthreads();
    for (int s = 128; s > 0; s >>= 1) {
        if (threadIdx.x < s) red[threadIdx.x] += red[threadIdx.x + s];
        __syncthreads();
    }
    if (threadIdx.x == 0) atomicAdd(&acc[0], red[0]);
}

// l1 + giou + ninst over proposals
__global__ __launch_bounds__(256) void box_kernel(
    const float* __restrict__ boxes, const float* __restrict__ gtbox,
    const float* __restrict__ w_val, const int* __restrict__ gt_ind,
    float* __restrict__ acc)
{
    int e = blockIdx.x * 256 + threadIdx.x;
    float l1 = 0.f, gl = 0.f, w = 0.f;
    if (e < N_B * N_PROP) {
        w = w_val[e];
        if (w > 0.f) {
            int b = e / N_PROP;
            int gi = gt_ind[e];
            const float* a = boxes + e * 4;
            const float* g = gtbox + (b * N_GT + gi) * 4;
            float nb[4], ng[4];
            for (int k = 0; k < 4; k++) { nb[k] = a[k] / S_IMG; ng[k] = g[k] / S_IMG; }
            l1 = w * (((fabsf(nb[0] - ng[0]) + fabsf(nb[1] - ng[1]))
                       + fabsf(nb[2] - ng[2])) + fabsf(nb[3] - ng[3]));
            gl = w * (1.f - giou_pair(nb, ng));
        }
    }
    __shared__ float r0[256], r1[256], r2[256];
    r0[threadIdx.x] = l1; r1[threadIdx.x] = gl; r2[threadIdx.x] = w;
    __syncthreads();
    for (int s = 128; s > 0; s >>= 1) {
        if (threadIdx.x < s) {
            r0[threadIdx.x] += r0[threadIdx.x + s];
            r1[threadIdx.x] += r1[threadIdx.x + s];
            r2[threadIdx.x] += r2[threadIdx.x + s];
        }
        __syncthreads();
    }
    if (threadIdx.x == 0) {
        atomicAdd(&acc[1], r0[0]);
        atomicAdd(&acc[2], r1[0]);
        atomicAdd(&acc[4], r2[0]);
    }
}

// per-(image, gt-slot) class projection of features: proj = sum_f w_mask[cls,f]*feat[f]
__global__ __launch_bounds__(256) void proj_kernel(
    const float* __restrict__ feat, const float* __restrict__ wm,
    const int* __restrict__ gtcls, float* __restrict__ proj)
{
    int bj = blockIdx.x;               // b*24 + j
    int b = bj / N_GT;
    int cls = gtcls[bj];
    const float* wrow = wm + cls * CF;
    const float* fb = feat + (size_t)b * CF * HF * HF;
    for (int pix = threadIdx.x; pix < HF * HF; pix += 256) {
        float a = 0.f;
        for (int f = 0; f < CF; f++) a = fmaf(wrow[f], fb[f * HF * HF + pix], a);
        proj[(size_t)bj * HF * HF + pix] = a;
    }
}

// mask dice loss: one block per proposal
__global__ __launch_bounds__(256) void mask_kernel(
    const float* __restrict__ boxes, const float* __restrict__ gtbox,
    const float* __restrict__ gmask, const float* __restrict__ w_val,
    const int* __restrict__ gt_ind, const float* __restrict__ proj,
    float* __restrict__ acc)
{
    int e = blockIdx.x;                // b*300 + i
    float w = w_val[e];
    if (w == 0.f) return;
    int b = e / N_PROP;
    int gi = gt_ind[e];
    const float* pb = boxes + e * 4;
    const float* gb = gtbox + (b * N_GT + gi) * 4;
    const float* pimg = proj + (size_t)(b * N_GT + gi) * HF * HF;
    const float* gimg = gmask + (size_t)(b * N_GT + gi) * HM * HM;
    const float fs = 64.0f / 896.0f;
    const float ms = 224.0f / 896.0f;
    float px1 = pb[0] * fs, py1 = pb[1] * fs, px2 = pb[2] * fs, py2 = pb[3] * fs;
    float gx1 = gb[0] * ms, gy1 = gb[1] * ms, gx2 = gb[2] * ms, gy2 = gb[3] * ms;

    float inter = 0.f, sp = 0.f, sg = 0.f;
    for (int g = threadIdx.x; g < TT * TT; g += 256) {
        int ty = g / TT, tx = g % TT;
        float qx = ((float)tx + 0.5f) / (float)TT;
        float qy = ((float)ty + 0.5f) / (float)TT;
        float X = px1 + (px2 - px1) * qx - 0.5f;
        float Y = py1 + (py2 - py1) * qy - 0.5f;
        float lg = bilin(pimg, HF, HF, X, Y);
        float mp = 1.f / (1.f + expf(-lg));
        float Xg = gx1 + (gx2 - gx1) * qx - 0.5f;
        float Yg = gy1 + (gy2 - gy1) * qy - 0.5f;
        float gc = bilin(gimg, HM, HM, Xg, Yg);
        inter += mp * gc;
        sp += mp;
        sg += gc;
    }
    __shared__ float r0[256], r1[256], r2[256];
    r0[threadIdx.x] = inter; r1[threadIdx.x] = sp; r2[threadIdx.x] = sg;
    __syncthreads();
    for (int s = 128; s > 0; s >>= 1) {
        if (threadIdx.x < s) {
            r0[threadIdx.x] += r0[threadIdx.x + s];
            r1[threadIdx.x] += r1[threadIdx.x + s];
            r2[threadIdx.x] += r2[threadIdx.x + s];
        }
        __syncthreads();
    }
    if (threadIdx.x == 0) {
        float term = (1.f - 2.f * r0[0] / (r1[0] + r2[0] + EPSV)) * w;
        atomicAdd(&acc[3], term);
    }
}

__global__ void fin_kernel(const float* __restrict__ acc, float* __restrict__ out) {
    if (threadIdx.x == 0) {
        float ninst = acc[4];
        out[0] = 2.0f * acc[0] / ninst;
        out[1] = 5.0f * acc[1] / ninst;
        out[2] = 2.0f * acc[2] / ninst;
        out[3] = 5.0f * acc[3] / ninst;
    }
}

// ---------- launch ----------

extern "C" void kernel_launch(void* const* d_in, const int* in_sizes, int n_in,
                              void* d_out, int out_size, void* d_ws, size_t ws_size,
                              hipStream_t stream)
{
    const float* logits = (const float*)d_in[0];
    const float* boxes  = (const float*)d_in[1];
    const float* feat   = (const float*)d_in[2];
    const float* wm     = (const float*)d_in[3];
    const int*   gtcls  = (const int*)d_in[4];
    const float* gtbox  = (const float*)d_in[5];
    const float* gmask  = (const float*)d_in[6];
    float* out = (float*)d_out;
    float* ws  = (float*)d_ws;

    float* acc   = ws;                       // 8 floats
    float* w_val = ws + 8;                   // 1200 floats
    int*   gt_in = (int*)(ws + 8 + 1200);    // 1200 ints
    float* proj  = ws + 8 + 1200 + 1200;     // 4*24*4096 floats = 1.5 MB

    hipLaunchKernelGGL(zero_acc, dim3(1), dim3(64), 0, stream, acc);
    hipLaunchKernelGGL(match_kernel, dim3(N_B), dim3(256), 0, stream,
                       logits, boxes, gtcls, gtbox, w_val, gt_in);
    hipLaunchKernelGGL(cls_kernel, dim3((N_B * N_PROP * N_CLS + 255) / 256), dim3(256), 0, stream,
                       logits, gtcls, w_val, gt_in, acc);
    hipLaunchKernelGGL(box_kernel, dim3((N_B * N_PROP + 255) / 256), dim3(256), 0, stream,
                       boxes, gtbox, w_val, gt_in, acc);
    hipLaunchKernelGGL(proj_kernel, dim3(N_B * N_GT), dim3(256), 0, stream,
                       feat, wm, gtcls, proj);
    hipLaunchKernelGGL(mask_kernel, dim3(N_B * N_PROP), dim3(256), 0, stream,
                       boxes, gtbox, gmask, w_val, gt_in, proj, acc);
    hipLaunchKernelGGL(fin_kernel, dim3(1), dim3(64), 0, stream, acc, out);
}

// Round 2
// 174.049 us; speedup vs baseline: 2.8471x; 2.8471x over previous
//
#include <hip/hip_runtime.h>
#include <math.h>

#define N_PROP 300
#define N_CLS  80
#define N_GT   24
#define N_B    4
#define CF     128
#define HF     64
#define HM     224
#define TT     28
#define ALPHA  0.25f
#define EPSV   1e-8f
#define CAND_K 10
#define CENTER_R 44.8f
#define S_IMG 896.0f

// ---------- device helpers ----------

__device__ __forceinline__ float iou_unnorm(const float* a, const float* g) {
    float lx = fmaxf(a[0], g[0]), ly = fmaxf(a[1], g[1]);
    float rx = fminf(a[2], g[2]), ry = fminf(a[3], g[3]);
    float w = fmaxf(rx - lx, 0.f), h = fmaxf(ry - ly, 0.f);
    float inter = w * h;
    float aa = fmaxf(a[2] - a[0], 0.f) * fmaxf(a[3] - a[1], 0.f);
    float ag = fmaxf(g[2] - g[0], 0.f) * fmaxf(g[3] - g[1], 0.f);
    float uni = aa + ag - inter;
    return inter / (uni + EPSV);
}

__device__ __forceinline__ float giou_pair(const float* a, const float* g) {
    float lx = fmaxf(a[0], g[0]), ly = fmaxf(a[1], g[1]);
    float rx = fminf(a[2], g[2]), ry = fminf(a[3], g[3]);
    float w = fmaxf(rx - lx, 0.f), h = fmaxf(ry - ly, 0.f);
    float inter = w * h;
    float aa = fmaxf(a[2] - a[0], 0.f) * fmaxf(a[3] - a[1], 0.f);
    float ag = fmaxf(g[2] - g[0], 0.f) * fmaxf(g[3] - g[1], 0.f);
    float uni = aa + ag - inter;
    float iou = inter / (uni + EPSV);
    float elx = fminf(a[0], g[0]), ely = fminf(a[1], g[1]);
    float erx = fmaxf(a[2], g[2]), ery = fmaxf(a[3], g[3]);
    float ew = fmaxf(erx - elx, 0.f), eh = fmaxf(ery - ely, 0.f);
    float enc = ew * eh;
    return iou - (enc - uni) / (enc + EPSV);
}

__device__ __forceinline__ float bilin(const float* img, int H, int W, float X, float Y) {
    float x0f = fminf(fmaxf(floorf(X), 0.f), (float)(W - 1));
    float y0f = fminf(fmaxf(floorf(Y), 0.f), (float)(H - 1));
    float wx = fminf(fmaxf(X - x0f, 0.f), 1.f);
    float wy = fminf(fmaxf(Y - y0f, 0.f), 1.f);
    int x0 = (int)x0f, y0 = (int)y0f;
    int x1 = min(x0 + 1, W - 1), y1 = min(y0 + 1, H - 1);
    float v00 = img[y0 * W + x0], v01 = img[y0 * W + x1];
    float v10 = img[y1 * W + x0], v11 = img[y1 * W + x1];
    return v00 * (1.f - wx) * (1.f - wy) + v01 * wx * (1.f - wy)
         + v10 * (1.f - wx) * wy + v11 * wx * wy;
}

// ---------- kernels ----------

// valid flags + zero match/acc. grid 5x256 covers 1200 proposals.
__global__ __launch_bounds__(256) void prep_kernel(
    const float* __restrict__ boxes, const float* __restrict__ gtbox,
    int* __restrict__ valid, int* __restrict__ match, float* __restrict__ acc)
{
    int e = blockIdx.x * 256 + threadIdx.x;
    if (e < 8) acc[e] = 0.f;
    if (e >= N_B * N_PROP) return;
    int b = e / N_PROP;
    const float* a = boxes + e * 4;
    float cx = (a[0] + a[2]) * 0.5f;
    float cy = (a[1] + a[3]) * 0.5f;
    int v = 0;
    const float* gb = gtbox + b * N_GT * 4;
    for (int j = 0; j < N_GT; j++) {
        const float* g = gb + j * 4;
        int in_gt = (cx >= g[0]) & (cx <= g[2]) & (cy >= g[1]) & (cy <= g[3]);
        float gcx = (g[0] + g[2]) * 0.5f;
        float gcy = (g[1] + g[3]) * 0.5f;
        int in_ct = (fabsf(cx - gcx) <= CENTER_R) & (fabsf(cy - gcy) <= CENTER_R);
        v |= (in_gt | in_ct);
    }
    valid[e] = v;
    match[e] = 0;
}

// cost matrix, column-major cost[(b*24+j)*300 + i]. grid covers 7200.
__global__ __launch_bounds__(256) void cost_kernel(
    const float* __restrict__ logits, const float* __restrict__ boxes,
    const int* __restrict__ gtcls, const float* __restrict__ gtbox,
    const int* __restrict__ valid, float* __restrict__ cost)
{
    int e = blockIdx.x * 256 + threadIdx.x;
    if (e >= N_B * N_GT * N_PROP) return;
    int i = e % N_PROP;
    int bj = e / N_PROP;
    int b = bj / N_GT;

    const float* a = boxes + (b * N_PROP + i) * 4;
    const float* g = gtbox + bj * 4;
    float cx = (a[0] + a[2]) * 0.5f;
    float cy = (a[1] + a[3]) * 0.5f;
    int in_gt = (cx >= g[0]) & (cx <= g[2]) & (cy >= g[1]) & (cy <= g[3]);
    float gcx = (g[0] + g[2]) * 0.5f;
    float gcy = (g[1] + g[3]) * 0.5f;
    int in_ct = (fabsf(cx - gcx) <= CENTER_R) & (fabsf(cy - gcy) <= CENTER_R);
    int in_both = in_gt & in_ct;

    float x = logits[(b * N_PROP + i) * N_CLS + gtcls[bj]];
    float p = 1.f / (1.f + expf(-x));
    float neg = (-logf(1.f - p + EPSV)) * (1.f - ALPHA) * (p * p);
    float pos = (-logf(p + EPSV)) * ALPHA * ((1.f - p) * (1.f - p));
    float clsc = 2.0f * (pos - neg);

    float nb[4], ng[4];
    for (int k = 0; k < 4; k++) { nb[k] = a[k] / S_IMG; ng[k] = g[k] / S_IMG; }
    float l1 = 5.0f * (((fabsf(nb[0] - ng[0]) + fabsf(nb[1] - ng[1]))
                        + fabsf(nb[2] - ng[2])) + fabsf(nb[3] - ng[3]));
    float ngiou = giou_pair(nb, ng);

    float cst = clsc + l1;
    cst = cst + 2.0f * (1.f - ngiou);
    cst = cst + (in_both ? 0.f : 1e5f);
    cst = cst + (valid[b * N_PROP + i] ? 0.f : 1e9f);
    cost[e] = cst;
}

// one block per (b, j): dyn_k + stable rank + match bits
__global__ __launch_bounds__(320) void colmatch_kernel(
    const float* __restrict__ boxes, const float* __restrict__ gtbox,
    const int* __restrict__ valid, const float* __restrict__ cost,
    int* __restrict__ match)
{
    int bj = blockIdx.x;
    int b = bj / N_GT;
    int j = bj % N_GT;
    int tid = threadIdx.x;
    __shared__ float s_cost[N_PROP];
    __shared__ float s_iou[N_PROP];
    __shared__ float s_gb[4];
    __shared__ int s_val[N_PROP];
    __shared__ int s_dynk;

    if (tid < 4) s_gb[tid] = gtbox[bj * 4 + tid];
    __syncthreads();
    if (tid < N_PROP) {
        s_cost[tid] = cost[bj * N_PROP + tid];
        int v = valid[b * N_PROP + tid];
        s_val[tid] = v;
        float a[4];
        const float* ap = boxes + (b * N_PROP + tid) * 4;
        a[0] = ap[0]; a[1] = ap[1]; a[2] = ap[2]; a[3] = ap[3];
        s_iou[tid] = v ? iou_unnorm(a, s_gb) : 0.f;
    }
    __syncthreads();

    if (tid == 0) {
        float t[CAND_K];
        #pragma unroll
        for (int k = 0; k < CAND_K; k++) t[k] = 0.f;
        #pragma unroll 4
        for (int i = 0; i < N_PROP; i++) {
            float v = s_iou[i];
            if (v > t[CAND_K - 1]) {
                int k = CAND_K - 1;
                while (k > 0 && t[k - 1] < v) { t[k] = t[k - 1]; k--; }
                t[k] = v;
            }
        }
        float s = 0.f;
        #pragma unroll
        for (int k = 0; k < CAND_K; k++) s += t[k];
        int dk = (int)s;
        s_dynk = max(1, min(dk, N_PROP));
    }
    __syncthreads();

    if (tid < N_PROP && s_val[tid]) {
        float ci = s_cost[tid];
        int r = 0;
        #pragma unroll 4
        for (int k = 0; k < N_PROP; k++) {
            float ck = s_cost[k];
            r += (ck < ci) || (ck == ci && k < tid);
        }
        if (r < s_dynk) atomicOr(&match[b * N_PROP + tid], 1 << j);
    }
}

// per-proposal resolution: argmin + multi-match + outputs
__global__ __launch_bounds__(256) void resolve_kernel(
    const float* __restrict__ cost, const int* __restrict__ valid,
    const int* __restrict__ match, float* __restrict__ w_val,
    int* __restrict__ gt_ind)
{
    int e = blockIdx.x * 256 + threadIdx.x;
    if (e >= N_B * N_PROP) return;
    int b = e / N_PROP;
    int i = e % N_PROP;
    float bestc = cost[(b * N_GT + 0) * N_PROP + i];
    int best = 0;
    for (int j = 1; j < N_GT; j++) {
        float cc = cost[(b * N_GT + j) * N_PROP + i];
        if (cc < bestc) { bestc = cc; best = j; }
    }
    int msk = match[e];
    if (__popc(msk) > 1) msk = 1 << best;
    int gi = msk ? (__ffs(msk) - 1) : best;
    gt_ind[e] = gi;
    w_val[e] = valid[e] ? 1.0f : 0.0f;
}

// focal classification loss over all (b, n, c)
__global__ __launch_bounds__(256) void cls_kernel(
    const float* __restrict__ logits, const int* __restrict__ gtcls,
    const float* __restrict__ w_val, const int* __restrict__ gt_ind,
    float* __restrict__ acc)
{
    int e = blockIdx.x * 256 + threadIdx.x;
    float term = 0.f;
    if (e < N_B * N_PROP * N_CLS) {
        int cls = e % N_CLS;
        int bi = e / N_CLS;
        int b = bi / N_PROP;
        float x = logits[e];
        int gi = gt_ind[bi];
        int mc = gtcls[b * N_GT + gi];
        float w = w_val[bi];
        float label = (cls == mc) ? w : 0.f;
        float p = 1.f / (1.f + expf(-x));
        float ce = fmaxf(x, 0.f) + log1pf(expf(-fabsf(x))) - x * label;
        float pt = p * label + (1.f - p) * (1.f - label);
        float at = ALPHA * label + (1.f - ALPHA) * (1.f - label);
        term = at * (1.f - pt) * (1.f - pt) * ce;
    }
    __shared__ float red[256];
    red[threadIdx.x] = term;
    __syncthreads();
    for (int s = 128; s > 0; s >>= 1) {
        if (threadIdx.x < s) red[threadIdx.x] += red[threadIdx.x + s];
        __syncthreads();
    }
    if (threadIdx.x == 0) atomicAdd(&acc[0], red[0]);
}

// l1 + giou + ninst over proposals
__global__ __launch_bounds__(256) void box_kernel(
    const float* __restrict__ boxes, const float* __restrict__ gtbox,
    const float* __restrict__ w_val, const int* __restrict__ gt_ind,
    float* __restrict__ acc)
{
    int e = blockIdx.x * 256 + threadIdx.x;
    float l1 = 0.f, gl = 0.f, w = 0.f;
    if (e < N_B * N_PROP) {
        w = w_val[e];
        if (w > 0.f) {
            int b = e / N_PROP;
            int gi = gt_ind[e];
            const float* a = boxes + e * 4;
            const float* g = gtbox + (b * N_GT + gi) * 4;
            float nb[4], ng[4];
            for (int k = 0; k < 4; k++) { nb[k] = a[k] / S_IMG; ng[k] = g[k] / S_IMG; }
            l1 = w * (((fabsf(nb[0] - ng[0]) + fabsf(nb[1] - ng[1]))
                       + fabsf(nb[2] - ng[2])) + fabsf(nb[3] - ng[3]));
            gl = w * (1.f - giou_pair(nb, ng));
        }
    }
    __shared__ float r0[256], r1[256], r2[256];
    r0[threadIdx.x] = l1; r1[threadIdx.x] = gl; r2[threadIdx.x] = w;
    __syncthreads();
    for (int s = 128; s > 0; s >>= 1) {
        if (threadIdx.x < s) {
            r0[threadIdx.x] += r0[threadIdx.x + s];
            r1[threadIdx.x] += r1[threadIdx.x + s];
            r2[threadIdx.x] += r2[threadIdx.x + s];
        }
        __syncthreads();
    }
    if (threadIdx.x == 0) {
        atomicAdd(&acc[1], r0[0]);
        atomicAdd(&acc[2], r1[0]);
        atomicAdd(&acc[4], r2[0]);
    }
}

// projection: block = (b, 256-pixel chunk). feat read exactly once.
// s_w layout [f][j]: per-f weights for all 24 gt slots contiguous -> float4 broadcast reads.
__global__ __launch_bounds__(256) void proj_kernel(
    const float* __restrict__ feat, const float* __restrict__ wm,
    const int* __restrict__ gtcls, float* __restrict__ proj)
{
    int blk = blockIdx.x;
    int b = blk >> 4;          // HF*HF/256 = 16 chunks
    int chunk = blk & 15;
    int tid = threadIdx.x;
    __shared__ float s_w[CF][N_GT];   // 12 KB
    for (int k = tid; k < N_GT * CF; k += 256) {
        int j = k / CF, f = k % CF;
        s_w[f][j] = wm[gtcls[b * N_GT + j] * CF + f];
    }
    __syncthreads();
    int pix = chunk * 256 + tid;
    const float* fb = feat + (size_t)b * CF * HF * HF + pix;
    float accv[N_GT];
    #pragma unroll
    for (int j = 0; j < N_GT; j++) accv[j] = 0.f;
    for (int f = 0; f < CF; f++) {
        float v = fb[(size_t)f * HF * HF];
        const float4* wrow = (const float4*)&s_w[f][0];
        #pragma unroll
        for (int q = 0; q < 6; q++) {
            float4 wv = wrow[q];
            accv[q * 4 + 0] = fmaf(wv.x, v, accv[q * 4 + 0]);
            accv[q * 4 + 1] = fmaf(wv.y, v, accv[q * 4 + 1]);
            accv[q * 4 + 2] = fmaf(wv.z, v, accv[q * 4 + 2]);
            accv[q * 4 + 3] = fmaf(wv.w, v, accv[q * 4 + 3]);
        }
    }
    #pragma unroll
    for (int j = 0; j < N_GT; j++)
        proj[((size_t)b * N_GT + j) * HF * HF + pix] = accv[j];
}

// mask dice loss: one block per proposal
__global__ __launch_bounds__(256) void mask_kernel(
    const float* __restrict__ boxes, const float* __restrict__ gtbox,
    const float* __restrict__ gmask, const float* __restrict__ w_val,
    const int* __restrict__ gt_ind, const float* __restrict__ proj,
    float* __restrict__ acc)
{
    int e = blockIdx.x;
    float w = w_val[e];
    if (w == 0.f) return;
    int b = e / N_PROP;
    int gi = gt_ind[e];
    const float* pb = boxes + e * 4;
    const float* gb = gtbox + (b * N_GT + gi) * 4;
    const float* pimg = proj + (size_t)(b * N_GT + gi) * HF * HF;
    const float* gimg = gmask + (size_t)(b * N_GT + gi) * HM * HM;
    const float fs = 64.0f / 896.0f;
    const float ms = 224.0f / 896.0f;
    float px1 = pb[0] * fs, py1 = pb[1] * fs, px2 = pb[2] * fs, py2 = pb[3] * fs;
    float gx1 = gb[0] * ms, gy1 = gb[1] * ms, gx2 = gb[2] * ms, gy2 = gb[3] * ms;

    float inter = 0.f, sp = 0.f, sg = 0.f;
    for (int g = threadIdx.x; g < TT * TT; g += 256) {
        int ty = g / TT, tx = g % TT;
        float qx = ((float)tx + 0.5f) / (float)TT;
        float qy = ((float)ty + 0.5f) / (float)TT;
        float X = px1 + (px2 - px1) * qx - 0.5f;
        float Y = py1 + (py2 - py1) * qy - 0.5f;
        float lg = bilin(pimg, HF, HF, X, Y);
        float mp = 1.f / (1.f + expf(-lg));
        float Xg = gx1 + (gx2 - gx1) * qx - 0.5f;
        float Yg = gy1 + (gy2 - gy1) * qy - 0.5f;
        float gc = bilin(gimg, HM, HM, Xg, Yg);
        inter += mp * gc;
        sp += mp;
        sg += gc;
    }
    __shared__ float r0[256], r1[256], r2[256];
    r0[threadIdx.x] = inter; r1[threadIdx.x] = sp; r2[threadIdx.x] = sg;
    __syncthreads();
    for (int s = 128; s > 0; s >>= 1) {
        if (threadIdx.x < s) {
            r0[threadIdx.x] += r0[threadIdx.x + s];
            r1[threadIdx.x] += r1[threadIdx.x + s];
            r2[threadIdx.x] += r2[threadIdx.x + s];
        }
        __syncthreads();
    }
    if (threadIdx.x == 0) {
        float term = (1.f - 2.f * r0[0] / (r1[0] + r2[0] + EPSV)) * w;
        atomicAdd(&acc[3], term);
    }
}

__global__ void fin_kernel(const float* __restrict__ acc, float* __restrict__ out) {
    if (threadIdx.x == 0) {
        float ninst = acc[4];
        out[0] = 2.0f * acc[0] / ninst;
        out[1] = 5.0f * acc[1] / ninst;
        out[2] = 2.0f * acc[2] / ninst;
        out[3] = 5.0f * acc[3] / ninst;
    }
}

// ---------- launch ----------

extern "C" void kernel_launch(void* const* d_in, const int* in_sizes, int n_in,
                              void* d_out, int out_size, void* d_ws, size_t ws_size,
                              hipStream_t stream)
{
    const float* logits = (const float*)d_in[0];
    const float* boxes  = (const float*)d_in[1];
    const float* feat   = (const float*)d_in[2];
    const float* wm     = (const float*)d_in[3];
    const int*   gtcls  = (const int*)d_in[4];
    const float* gtbox  = (const float*)d_in[5];
    const float* gmask  = (const float*)d_in[6];
    float* out = (float*)d_out;
    float* ws  = (float*)d_ws;

    float* acc   = ws;                                  // 8 floats
    float* w_val = ws + 8;                              // 1200
    int*   gt_in = (int*)(ws + 8 + 1200);               // 1200
    int*   valid = (int*)(ws + 8 + 2400);               // 1200
    int*   match = (int*)(ws + 8 + 3600);               // 1200
    float* cost  = ws + 8 + 4800;                       // 28800
    float* proj  = ws + 8 + 4800 + 28800;               // 393216

    hipLaunchKernelGGL(prep_kernel, dim3(5), dim3(256), 0, stream,
                       boxes, gtbox, valid, match, acc);
    hipLaunchKernelGGL(cost_kernel, dim3((N_B * N_GT * N_PROP + 255) / 256), dim3(256), 0, stream,
                       logits, boxes, gtcls, gtbox, valid, cost);
    hipLaunchKernelGGL(colmatch_kernel, dim3(N_B * N_GT), dim3(320), 0, stream,
                       boxes, gtbox, valid, cost, match);
    hipLaunchKernelGGL(resolve_kernel, dim3(5), dim3(256), 0, stream,
                       cost, valid, match, w_val, gt_in);
    hipLaunchKernelGGL(cls_kernel, dim3((N_B * N_PROP * N_CLS + 255) / 256), dim3(256), 0, stream,
                       logits, gtcls, w_val, gt_in, acc);
    hipLaunchKernelGGL(box_kernel, dim3((N_B * N_PROP + 255) / 256), dim3(256), 0, stream,
                       boxes, gtbox, w_val, gt_in, acc);
    hipLaunchKernelGGL(proj_kernel, dim3(N_B * 16), dim3(256), 0, stream,
                       feat, wm, gtcls, proj);
    hipLaunchKernelGGL(mask_kernel, dim3(N_B * N_PROP), dim3(256), 0, stream,
                       boxes, gtbox, gmask, w_val, gt_in, proj, acc);
    hipLaunchKernelGGL(fin_kernel, dim3(1), dim3(64), 0, stream, acc, out);
}